// Round 11
// baseline (307.366 us; speedup 1.0000x reference)
//
#include <hip/hip_runtime.h>

// GCN 3-layer (PyG GCNConv: self-loops + D^-1/2 A D^-1/2).
// R10 (resubmitted R11 after acquisition timeout): k_gemm64 broadcast via LDS
// (same-address ds_read = HW broadcast) instead of v_readlane (R9: 51us —
// readlane->SGPR->VALU wait-state hazard per fma, 512 pairs/batch). Wave
// stages 8 node-rows in LDS (4 coalesced loads), W streamed once per 8 nodes:
// 88 wave-inst/node. Everything else = R9.

#define SHIFT 9
#define BW_ (1 << SHIFT)      // 512 nodes per bucket
#define ITEMS 16              // edges per thread in k_partition

__device__ __forceinline__ float blo(unsigned w) { return __uint_as_float(w << 16); }
__device__ __forceinline__ float bhi(unsigned w) { return __uint_as_float(w & 0xffff0000u); }
__device__ __forceinline__ unsigned packbf(float a, float b) {
    unsigned ua = __float_as_uint(a), ub = __float_as_uint(b);
    ua = (ua + 0x7fffu + ((ua >> 16) & 1u)) >> 16;         // RN-even
    ub = (ub + 0x7fffu + ((ub >> 16) & 1u)) & 0xffff0000u;
    return ua | ub;
}

__global__ __launch_bounds__(256) void k_partition(
    const int* __restrict__ src, const int* __restrict__ dst, int E,
    int* __restrict__ bcur, unsigned* __restrict__ words, int cap) {
    __shared__ int cnt[256];
    __shared__ int gbase[256];
    int t = threadIdx.x;
    int base = blockIdx.x * (256 * ITEMS);
    cnt[t] = 0;
    __syncthreads();
    unsigned w[ITEMS]; int b[ITEMS], r[ITEMS];
    #pragma unroll
    for (int j = 0; j < ITEMS; ++j) {
        int e = base + j * 256 + t;
        if (e < E) {
            int d = dst[e], s = src[e];
            b[j] = d >> SHIFT;
            w[j] = ((unsigned)s << SHIFT) | (unsigned)(d & (BW_ - 1));
            r[j] = atomicAdd(&cnt[b[j]], 1);     // LDS atomic
        } else b[j] = -1;
    }
    __syncthreads();
    int c = cnt[t];
    gbase[t] = c ? atomicAdd(&bcur[t], c) : 0;
    __syncthreads();
    #pragma unroll
    for (int j = 0; j < ITEMS; ++j) {
        if (b[j] >= 0) {
            int idx = gbase[b[j]] + r[j];
            if (idx < cap)
                words[(size_t)b[j] * cap + idx] = w[j];
        }
    }
}

__global__ __launch_bounds__(512) void k_hist(
    const unsigned* __restrict__ words, const int* __restrict__ bcnt, int cap,
    int* __restrict__ deg, int N) {
    __shared__ int h[BW_];
    int b = blockIdx.x, t = threadIdx.x;
    h[t] = 0;
    __syncthreads();
    int n = min(bcnt[b], cap);
    const unsigned* wb = words + (size_t)b * cap;
    for (int i = t; i < n; i += 512)
        atomicAdd(&h[wb[i] & (BW_ - 1)], 1);
    __syncthreads();
    int node = b * BW_ + t;
    if (node < N) deg[node] = h[t];
}

__global__ __launch_bounds__(512) void k_place(
    const unsigned* __restrict__ words, const int* __restrict__ bcnt, int cap,
    const int* __restrict__ rowptr, int* __restrict__ col, int N) {
    __shared__ int cur[BW_];
    int b = blockIdx.x, t = threadIdx.x;
    int node = b * BW_ + t;
    cur[t] = (node < N) ? rowptr[node] : 0;
    __syncthreads();
    int n = min(bcnt[b], cap);
    const unsigned* wb = words + (size_t)b * cap;
    for (int i = t; i < n; i += 512) {
        unsigned w = wb[i];
        int p = atomicAdd(&cur[w & (BW_ - 1)], 1);
        col[p] = (int)(w >> SHIFT);
    }
}

__global__ void k_scan1(const int* __restrict__ deg, int N,
                        int* __restrict__ rowptr, int* __restrict__ bsum) {
    __shared__ int lds[256];
    int t = threadIdx.x;
    int i = blockIdx.x * 256 + t;
    int v = (i < N) ? deg[i] : 0;
    lds[t] = v; __syncthreads();
    #pragma unroll
    for (int off = 1; off < 256; off <<= 1) {
        int tmp = (t >= off) ? lds[t - off] : 0; __syncthreads();
        lds[t] += tmp; __syncthreads();
    }
    if (i < N) rowptr[i] = lds[t] - v;
    if (t == 255) bsum[blockIdx.x] = lds[255];
}

__global__ void k_scan2(const int* __restrict__ bsum, int nb, int* __restrict__ boff) {
    __shared__ int lds[1024];
    int t = threadIdx.x;
    int v = (t < nb) ? bsum[t] : 0;
    lds[t] = v; __syncthreads();
    #pragma unroll
    for (int off = 1; off < 1024; off <<= 1) {
        int tmp = (t >= off) ? lds[t - off] : 0; __syncthreads();
        lds[t] += tmp; __syncthreads();
    }
    if (t < nb) boff[t] = lds[t] - v;
    if (t == 0) boff[nb] = lds[1023];
}

__global__ void k_scan3(const int* __restrict__ boff, int N, int nb,
                        int* __restrict__ rowptr, const int* __restrict__ deg,
                        float* __restrict__ dinv) {
    int i = blockIdx.x * blockDim.x + threadIdx.x;
    if (i < N) {
        rowptr[i] += boff[i >> 8];
        dinv[i] = rsqrtf((float)deg[i] + 1.0f);
    } else if (i == N) {
        rowptr[N] = boff[nb];
    }
}

// hw1[n] packed: uint f = bf16(dinv*(x*W1[0,2f]+c0)) | bf16(...2f+1)<<16
__global__ void k_layer1(const float* __restrict__ x, const float* __restrict__ delta,
                         const float* __restrict__ W1, const float* __restrict__ dinv,
                         unsigned* __restrict__ hw, int N) {
    int idx = blockIdx.x * blockDim.x + threadIdx.x;
    if (idx >= N * 32) return;
    int n = idx >> 5, f = idx & 31;
    int d0 = 2 * f, d1 = 2 * f + 1;
    float c0 = delta[0] * W1[64 + d0] + delta[1] * W1[128 + d0] +
               delta[2] * W1[192 + d0] + delta[3] * W1[256 + d0];
    float c1 = delta[0] * W1[64 + d1] + delta[1] * W1[128 + d1] +
               delta[2] * W1[192 + d1] + delta[3] * W1[256 + d1];
    float dn = dinv[n], xv = x[n];
    hw[idx] = packbf(dn * fmaf(xv, W1[d0], c0), dn * fmaf(xv, W1[d1], c1));
}

// Gather one <=64-edge chunk, 16 edges per group (8 loads in flight).
__device__ __forceinline__ void gather16(const unsigned* __restrict__ hw,
                                         int s, int cnt, int fb, int half,
                                         float& a0, float& a1) {
    for (int j = 0; j < cnt; j += 16) {
        unsigned v[8]; int e[8];
        #pragma unroll
        for (int g = 0; g < 8; ++g) {
            e[g] = j + 2 * g + half;
            int idx = __shfl(s, min(e[g], cnt - 1));
            v[g] = hw[(size_t)idx * 32 + fb];
        }
        #pragma unroll
        for (int g = 0; g < 8; ++g) {
            unsigned w = (e[g] < cnt) ? v[g] : 0u;
            a0 += blo(w); a1 += bhi(w);
        }
    }
}

// Pure gather + relu + pack: h2 = relu(dinv*agg + b).
__global__ __launch_bounds__(256) void k_agg1(
    const unsigned* __restrict__ hw_in, const int* __restrict__ rowptr,
    const int* __restrict__ col, const float* __restrict__ dinv,
    const float* __restrict__ bias, unsigned* __restrict__ h2u, int N) {
    int lane = threadIdx.x & 63;
    int fb = lane & 31, half = lane >> 5;
    float b0 = bias[2 * fb], b1 = bias[2 * fb + 1];
    int stride = gridDim.x * 4;
    int n = blockIdx.x * 4 + (threadIdx.x >> 6);
    int rs = 0, re = 0;
    if (n < N) { rs = rowptr[n]; re = rowptr[n + 1]; }
    int cnt0 = min(64, re - rs);
    int s = (cnt0 > 0) ? col[rs + min(lane, cnt0 - 1)] : 0;
    while (n < N) {
        int n2 = n + stride;
        int rs2 = 0, re2 = 0;
        if (n2 < N) { rs2 = rowptr[n2]; re2 = rowptr[n2 + 1]; }
        int cnt2 = min(64, re2 - rs2);
        int s2 = (cnt2 > 0) ? col[rs2 + min(lane, cnt2 - 1)] : 0;  // prefetch next
        unsigned sw = hw_in[(size_t)n * 32 + fb];                  // self-loop
        float a0 = 0.f, a1 = 0.f;
        gather16(hw_in, s, cnt0, fb, half, a0, a1);
        for (int base = rs + 64; base < re; base += 64) {          // rare: deg>64
            int cc = min(64, re - base);
            int sx = col[base + min(lane, cc - 1)];
            gather16(hw_in, sx, cc, fb, half, a0, a1);
        }
        a0 += __shfl_xor(a0, 32);
        a1 += __shfl_xor(a1, 32);
        a0 += blo(sw); a1 += bhi(sw);
        float dn = dinv[n];
        float t0 = fmaxf(fmaf(dn, a0, b0), 0.0f);
        float t1 = fmaxf(fmaf(dn, a1, b1), 0.0f);
        if (half == 0) h2u[(size_t)n * 32 + fb] = packbf(t0, t1);
        n = n2; rs = rs2; re = re2; cnt0 = cnt2; s = s2;
    }
}

// Dense hw2 = dinv * (h2 @ W2). 8 nodes/wave staged in LDS; inner loop is
// broadcast ds_read_b64 (same-address = HW broadcast) + 4 fma; W streamed
// once per 8 nodes (L1 traffic /8). ~88 wave-inst/node, VGPR ~30.
__global__ __launch_bounds__(256) void k_gemm64(
    const unsigned* __restrict__ h2u, const float* __restrict__ dinv,
    const float* __restrict__ W, unsigned* __restrict__ hw2, int N) {
    __shared__ unsigned tbuf[4][8][32];          // 4 waves x 8 rows x 128B = 4KB
    int lane = threadIdx.x & 63, wave = threadIdx.x >> 6;
    int q = lane & 31, h = lane >> 5;
    int nb = (blockIdx.x * 4 + wave) * 8;
    if (nb >= N) return;
    #pragma unroll
    for (int i = 0; i < 4; ++i) {                // stage 8 rows, 4 coalesced loads
        int m = i * 2 + h;
        int node = min(nb + m, N - 1);           // tail: clamp (store guarded)
        tbuf[wave][m][q] = h2u[(size_t)node * 32 + q];
    }
    __builtin_amdgcn_wave_barrier();
    float o[8];
    #pragma unroll
    for (int m = 0; m < 8; ++m) o[m] = 0.f;
    #pragma unroll
    for (int k4 = 0; k4 < 16; ++k4) {
        float w0 = W[(4 * k4 + 0) * 64 + lane];
        float w1 = W[(4 * k4 + 1) * 64 + lane];
        float w2 = W[(4 * k4 + 2) * 64 + lane];
        float w3 = W[(4 * k4 + 3) * 64 + lane];
        #pragma unroll
        for (int m = 0; m < 8; ++m) {
            uint2 u = *(const uint2*)&tbuf[wave][m][k4 * 2];   // broadcast b64
            o[m] = fmaf(blo(u.x), w0, o[m]);
            o[m] = fmaf(bhi(u.x), w1, o[m]);
            o[m] = fmaf(blo(u.y), w2, o[m]);
            o[m] = fmaf(bhi(u.y), w3, o[m]);
        }
    }
    #pragma unroll
    for (int m = 0; m < 8; ++m) {
        int nn = nb + m;
        if (nn < N) {
            float v = dinv[nn] * o[m];
            float v2 = __shfl_down(v, 1);
            if ((lane & 1) == 0)
                hw2[(size_t)nn * 32 + (lane >> 1)] = packbf(v, v2);
        }
    }
}

// Gather hw2 + relu + W3 (64x3) reduce -> hw3 float4.
__global__ __launch_bounds__(256, 4) void k_agg2(
    const unsigned* __restrict__ hw_in, const int* __restrict__ rowptr,
    const int* __restrict__ col, const float* __restrict__ dinv,
    const float* __restrict__ bias, const float* __restrict__ W3,
    float4* __restrict__ hw3, int N) {
    int lane = threadIdx.x & 63, wave = threadIdx.x >> 6;
    int fb = lane & 31, half = lane >> 5;
    int d0 = 2 * fb, d1 = 2 * fb + 1;
    float wa0 = W3[d0 * 3 + 0], wa1 = W3[d0 * 3 + 1], wa2 = W3[d0 * 3 + 2];
    float wb0 = W3[d1 * 3 + 0], wb1 = W3[d1 * 3 + 1], wb2 = W3[d1 * 3 + 2];
    float b0 = bias[d0], b1 = bias[d1];
    int stride = gridDim.x * 4;
    int n = blockIdx.x * 4 + wave;
    int rs = 0, re = 0;
    if (n < N) { rs = rowptr[n]; re = rowptr[n + 1]; }
    int cnt0 = min(64, re - rs);
    int s = (cnt0 > 0) ? col[rs + min(lane, cnt0 - 1)] : 0;
    while (n < N) {
        int n2 = n + stride;
        int rs2 = 0, re2 = 0;
        if (n2 < N) { rs2 = rowptr[n2]; re2 = rowptr[n2 + 1]; }
        int cnt2 = min(64, re2 - rs2);
        int s2 = (cnt2 > 0) ? col[rs2 + min(lane, cnt2 - 1)] : 0;
        unsigned sw = hw_in[(size_t)n * 32 + fb];
        float a0 = 0.f, a1 = 0.f;
        gather16(hw_in, s, cnt0, fb, half, a0, a1);
        for (int base = rs + 64; base < re; base += 64) {
            int cc = min(64, re - base);
            int sx = col[base + min(lane, cc - 1)];
            gather16(hw_in, sx, cc, fb, half, a0, a1);
        }
        a0 += __shfl_xor(a0, 32);
        a1 += __shfl_xor(a1, 32);
        a0 += blo(sw); a1 += bhi(sw);
        float dn = dinv[n];
        float t0 = fmaxf(fmaf(dn, a0, b0), 0.0f);
        float t1 = fmaxf(fmaf(dn, a1, b1), 0.0f);
        float p0 = fmaf(t0, wa0, t1 * wb0);
        float p1 = fmaf(t0, wa1, t1 * wb1);
        float p2 = fmaf(t0, wa2, t1 * wb2);
        #pragma unroll
        for (int off = 16; off; off >>= 1) {     // halves identical: reduce 32
            p0 += __shfl_xor(p0, off);
            p1 += __shfl_xor(p1, off);
            p2 += __shfl_xor(p2, off);
        }
        if (lane == 0) hw3[n] = make_float4(dn * p0, dn * p1, dn * p2, 0.f);
        n = n2; rs = rs2; re = re2; cnt0 = cnt2; s = s2;
    }
}

__global__ __launch_bounds__(256) void k_final(
    const float4* __restrict__ hw3, const int* __restrict__ rowptr,
    const int* __restrict__ col, const float* __restrict__ dinv,
    const float* __restrict__ b3, const float* __restrict__ x,
    const float* __restrict__ pos, float* __restrict__ out, int N) {
    int lane = threadIdx.x & 63, wave = threadIdx.x >> 6;
    int n = blockIdx.x * 4 + wave;
    if (n >= N) return;
    int rs = rowptr[n], re = rowptr[n + 1];
    float a0 = 0.f, a1 = 0.f, a2 = 0.f;
    for (int i = rs + lane; i < re; i += 64) {
        float4 v = hw3[col[i]];
        a0 += v.x; a1 += v.y; a2 += v.z;
    }
    #pragma unroll
    for (int off = 32; off; off >>= 1) {
        a0 += __shfl_xor(a0, off);
        a1 += __shfl_xor(a1, off);
        a2 += __shfl_xor(a2, off);
    }
    if (lane == 0) {
        float4 sv = hw3[n];
        a0 += sv.x; a1 += sv.y; a2 += sv.z;
        float dn = dinv[n];
        float o0 = fmaf(dn, a0, b3[0]);
        float o1 = fmaf(dn, a1, b3[1]);
        float o2 = fmaf(dn, a2, b3[2]);
        out[n] = x[n] + o2;
        out[N + 2 * n]     = pos[2 * n]     + o0;
        out[N + 2 * n + 1] = pos[2 * n + 1] + o1;
    }
}

extern "C" void kernel_launch(void* const* d_in, const int* in_sizes, int n_in,
                              void* d_out, int out_size, void* d_ws, size_t ws_size,
                              hipStream_t stream) {
    const float* x     = (const float*)d_in[0];
    const float* pos   = (const float*)d_in[1];
    const float* delta = (const float*)d_in[2];
    const int*   ei    = (const int*)  d_in[3];
    const float* W1    = (const float*)d_in[4];
    const float* b1    = (const float*)d_in[5];
    const float* W2    = (const float*)d_in[6];
    const float* b2    = (const float*)d_in[7];
    const float* W3    = (const float*)d_in[8];
    const float* b3    = (const float*)d_in[9];
    int N = in_sizes[0];
    int E = in_sizes[3] / 2;
    const int* src = ei;
    const int* dst = ei + E;

    char* p = (char*)d_ws;
    auto alloc = [&](size_t bytes) {
        char* r = p; p += (bytes + 255) & ~(size_t)255; return r;
    };
    int*   deg    = (int*)  alloc((size_t)N * 4);
    int*   bcur   = (int*)  alloc(256 * 4);
    int*   rowptr = (int*)  alloc((size_t)(N + 1) * 4);
    int nb1 = (N + 255) / 256;
    int*   bsum   = (int*)  alloc((size_t)nb1 * 4);
    int*   boff   = (int*)  alloc((size_t)(nb1 + 1) * 4);
    float* dinv   = (float*)alloc((size_t)N * 4);
    int*   col    = (int*)  alloc((size_t)E * 4);
    unsigned* hw1 = (unsigned*)alloc((size_t)N * 32 * 4);  // bf16x2 packed
    unsigned* hw2 = (unsigned*)alloc((size_t)N * 32 * 4);

    int B   = (N + BW_ - 1) >> SHIFT;   // 196 buckets for N=100K
    int cap = 2 * (E / B) + 1024;
    size_t wbytes = (size_t)B * cap * 4;                   // ~13.6MB
    size_t h2bytes = (size_t)N * 32 * 4;                   // 12.8MB
    unsigned* words = (unsigned*)alloc(wbytes > h2bytes ? wbytes : h2bytes);
    unsigned* h2u   = words;            // words dead after k_place
    float4*   hw3   = (float4*)hw1;     // hw1 dead after k_agg1

    int npb = (E + (256 * ITEMS) - 1) / (256 * ITEMS);

    hipMemsetAsync(bcur, 0, 256 * 4, stream);
    k_partition<<<npb, 256, 0, stream>>>(src, dst, E, bcur, words, cap);
    k_hist<<<B, 512, 0, stream>>>(words, bcur, cap, deg, N);
    k_scan1<<<nb1, 256, 0, stream>>>(deg, N, rowptr, bsum);
    k_scan2<<<1, 1024, 0, stream>>>(bsum, nb1, boff);
    k_scan3<<<(N + 256) / 256, 256, 0, stream>>>(boff, N, nb1, rowptr, deg, dinv);
    k_place<<<B, 512, 0, stream>>>(words, bcur, cap, rowptr, col, N);
    k_layer1<<<(N * 32 + 255) / 256, 256, 0, stream>>>(x, delta, W1, dinv, hw1, N);
    k_agg1<<<2048, 256, 0, stream>>>(hw1, rowptr, col, dinv, b1, h2u, N);
    k_gemm64<<<(N + 31) / 32, 256, 0, stream>>>(h2u, dinv, W2, hw2, N);
    k_agg2<<<2048, 256, 0, stream>>>(hw2, rowptr, col, dinv, b2, W3, hw3, N);
    k_final<<<(N + 3) / 4, 256, 0, stream>>>(hw3, rowptr, col, dinv, b3, x, pos,
                                             (float*)d_out, N);
}

// Round 12
// 262.040 us; speedup vs baseline: 1.1730x; 1.1730x over previous
//
#include <hip/hip_runtime.h>

// GCN 3-layer (PyG GCNConv: self-loops + D^-1/2 A D^-1/2).
// R12: dense hw2 = dinv*(h2@W2) via MFMA (Guideline 10). R9 (readlane, 51us)
// and R11 (LDS broadcast, 62us, VGPR=152 from hoisted unroll) prove scalar-FMA
// codegen is fragile. Wave = 16-node x 64-col tile, K=64 in 2 steps of 32:
// 8 x mfma_f32_16x16x32_bf16. W2 pre-packed bf16 (k-pair per uint) by k_packw,
// all 8 B-frags (32 VGPR) loaded once per wave. A-frag = 1 uint4/kstep.

#define SHIFT 9
#define BW_ (1 << SHIFT)      // 512 nodes per bucket
#define ITEMS 16              // edges per thread in k_partition

typedef __attribute__((ext_vector_type(8))) short bf16x8;
typedef __attribute__((ext_vector_type(4))) float f32x4;

__device__ __forceinline__ float blo(unsigned w) { return __uint_as_float(w << 16); }
__device__ __forceinline__ float bhi(unsigned w) { return __uint_as_float(w & 0xffff0000u); }
__device__ __forceinline__ unsigned packbf(float a, float b) {
    unsigned ua = __float_as_uint(a), ub = __float_as_uint(b);
    ua = (ua + 0x7fffu + ((ua >> 16) & 1u)) >> 16;         // RN-even
    ub = (ub + 0x7fffu + ((ub >> 16) & 1u)) & 0xffff0000u;
    return ua | ub;
}

__global__ __launch_bounds__(256) void k_partition(
    const int* __restrict__ src, const int* __restrict__ dst, int E,
    int* __restrict__ bcur, unsigned* __restrict__ words, int cap) {
    __shared__ int cnt[256];
    __shared__ int gbase[256];
    int t = threadIdx.x;
    int base = blockIdx.x * (256 * ITEMS);
    cnt[t] = 0;
    __syncthreads();
    unsigned w[ITEMS]; int b[ITEMS], r[ITEMS];
    #pragma unroll
    for (int j = 0; j < ITEMS; ++j) {
        int e = base + j * 256 + t;
        if (e < E) {
            int d = dst[e], s = src[e];
            b[j] = d >> SHIFT;
            w[j] = ((unsigned)s << SHIFT) | (unsigned)(d & (BW_ - 1));
            r[j] = atomicAdd(&cnt[b[j]], 1);     // LDS atomic
        } else b[j] = -1;
    }
    __syncthreads();
    int c = cnt[t];
    gbase[t] = c ? atomicAdd(&bcur[t], c) : 0;
    __syncthreads();
    #pragma unroll
    for (int j = 0; j < ITEMS; ++j) {
        if (b[j] >= 0) {
            int idx = gbase[b[j]] + r[j];
            if (idx < cap)
                words[(size_t)b[j] * cap + idx] = w[j];
        }
    }
}

__global__ __launch_bounds__(512) void k_hist(
    const unsigned* __restrict__ words, const int* __restrict__ bcnt, int cap,
    int* __restrict__ deg, int N) {
    __shared__ int h[BW_];
    int b = blockIdx.x, t = threadIdx.x;
    h[t] = 0;
    __syncthreads();
    int n = min(bcnt[b], cap);
    const unsigned* wb = words + (size_t)b * cap;
    for (int i = t; i < n; i += 512)
        atomicAdd(&h[wb[i] & (BW_ - 1)], 1);
    __syncthreads();
    int node = b * BW_ + t;
    if (node < N) deg[node] = h[t];
}

__global__ __launch_bounds__(512) void k_place(
    const unsigned* __restrict__ words, const int* __restrict__ bcnt, int cap,
    const int* __restrict__ rowptr, int* __restrict__ col, int N) {
    __shared__ int cur[BW_];
    int b = blockIdx.x, t = threadIdx.x;
    int node = b * BW_ + t;
    cur[t] = (node < N) ? rowptr[node] : 0;
    __syncthreads();
    int n = min(bcnt[b], cap);
    const unsigned* wb = words + (size_t)b * cap;
    for (int i = t; i < n; i += 512) {
        unsigned w = wb[i];
        int p = atomicAdd(&cur[w & (BW_ - 1)], 1);
        col[p] = (int)(w >> SHIFT);
    }
}

__global__ void k_scan1(const int* __restrict__ deg, int N,
                        int* __restrict__ rowptr, int* __restrict__ bsum) {
    __shared__ int lds[256];
    int t = threadIdx.x;
    int i = blockIdx.x * 256 + t;
    int v = (i < N) ? deg[i] : 0;
    lds[t] = v; __syncthreads();
    #pragma unroll
    for (int off = 1; off < 256; off <<= 1) {
        int tmp = (t >= off) ? lds[t - off] : 0; __syncthreads();
        lds[t] += tmp; __syncthreads();
    }
    if (i < N) rowptr[i] = lds[t] - v;
    if (t == 255) bsum[blockIdx.x] = lds[255];
}

__global__ void k_scan2(const int* __restrict__ bsum, int nb, int* __restrict__ boff) {
    __shared__ int lds[1024];
    int t = threadIdx.x;
    int v = (t < nb) ? bsum[t] : 0;
    lds[t] = v; __syncthreads();
    #pragma unroll
    for (int off = 1; off < 1024; off <<= 1) {
        int tmp = (t >= off) ? lds[t - off] : 0; __syncthreads();
        lds[t] += tmp; __syncthreads();
    }
    if (t < nb) boff[t] = lds[t] - v;
    if (t == 0) boff[nb] = lds[1023];
}

__global__ void k_scan3(const int* __restrict__ boff, int N, int nb,
                        int* __restrict__ rowptr, const int* __restrict__ deg,
                        float* __restrict__ dinv) {
    int i = blockIdx.x * blockDim.x + threadIdx.x;
    if (i < N) {
        rowptr[i] += boff[i >> 8];
        dinv[i] = rsqrtf((float)deg[i] + 1.0f);
    } else if (i == N) {
        rowptr[N] = boff[nb];
    }
}

// hw1[n] packed: uint f = bf16(dinv*(x*W1[0,2f]+c0)) | bf16(...2f+1)<<16
__global__ void k_layer1(const float* __restrict__ x, const float* __restrict__ delta,
                         const float* __restrict__ W1, const float* __restrict__ dinv,
                         unsigned* __restrict__ hw, int N) {
    int idx = blockIdx.x * blockDim.x + threadIdx.x;
    if (idx >= N * 32) return;
    int n = idx >> 5, f = idx & 31;
    int d0 = 2 * f, d1 = 2 * f + 1;
    float c0 = delta[0] * W1[64 + d0] + delta[1] * W1[128 + d0] +
               delta[2] * W1[192 + d0] + delta[3] * W1[256 + d0];
    float c1 = delta[0] * W1[64 + d1] + delta[1] * W1[128 + d1] +
               delta[2] * W1[192 + d1] + delta[3] * W1[256 + d1];
    float dn = dinv[n], xv = x[n];
    hw[idx] = packbf(dn * fmaf(xv, W1[d0], c0), dn * fmaf(xv, W1[d1], c1));
}

// W2 (fp32 [64][64], k-major) -> wp[d][kk]: bf16 pair (W2[2kk][d], W2[2kk+1][d])
__global__ void k_packw(const float* __restrict__ W, unsigned* __restrict__ wp) {
    int i = blockIdx.x * blockDim.x + threadIdx.x;
    if (i >= 64 * 32) return;
    int d = i >> 5, kk = i & 31;
    wp[i] = packbf(W[(2 * kk) * 64 + d], W[(2 * kk + 1) * 64 + d]);
}

// Gather one <=64-edge chunk, 16 edges per group (8 loads in flight).
__device__ __forceinline__ void gather16(const unsigned* __restrict__ hw,
                                         int s, int cnt, int fb, int half,
                                         float& a0, float& a1) {
    for (int j = 0; j < cnt; j += 16) {
        unsigned v[8]; int e[8];
        #pragma unroll
        for (int g = 0; g < 8; ++g) {
            e[g] = j + 2 * g + half;
            int idx = __shfl(s, min(e[g], cnt - 1));
            v[g] = hw[(size_t)idx * 32 + fb];
        }
        #pragma unroll
        for (int g = 0; g < 8; ++g) {
            unsigned w = (e[g] < cnt) ? v[g] : 0u;
            a0 += blo(w); a1 += bhi(w);
        }
    }
}

// Pure gather + relu + pack: h2 = relu(dinv*agg + b).
__global__ __launch_bounds__(256) void k_agg1(
    const unsigned* __restrict__ hw_in, const int* __restrict__ rowptr,
    const int* __restrict__ col, const float* __restrict__ dinv,
    const float* __restrict__ bias, unsigned* __restrict__ h2u, int N) {
    int lane = threadIdx.x & 63;
    int fb = lane & 31, half = lane >> 5;
    float b0 = bias[2 * fb], b1 = bias[2 * fb + 1];
    int stride = gridDim.x * 4;
    int n = blockIdx.x * 4 + (threadIdx.x >> 6);
    int rs = 0, re = 0;
    if (n < N) { rs = rowptr[n]; re = rowptr[n + 1]; }
    int cnt0 = min(64, re - rs);
    int s = (cnt0 > 0) ? col[rs + min(lane, cnt0 - 1)] : 0;
    while (n < N) {
        int n2 = n + stride;
        int rs2 = 0, re2 = 0;
        if (n2 < N) { rs2 = rowptr[n2]; re2 = rowptr[n2 + 1]; }
        int cnt2 = min(64, re2 - rs2);
        int s2 = (cnt2 > 0) ? col[rs2 + min(lane, cnt2 - 1)] : 0;  // prefetch next
        unsigned sw = hw_in[(size_t)n * 32 + fb];                  // self-loop
        float a0 = 0.f, a1 = 0.f;
        gather16(hw_in, s, cnt0, fb, half, a0, a1);
        for (int base = rs + 64; base < re; base += 64) {          // rare: deg>64
            int cc = min(64, re - base);
            int sx = col[base + min(lane, cc - 1)];
            gather16(hw_in, sx, cc, fb, half, a0, a1);
        }
        a0 += __shfl_xor(a0, 32);
        a1 += __shfl_xor(a1, 32);
        a0 += blo(sw); a1 += bhi(sw);
        float dn = dinv[n];
        float t0 = fmaxf(fmaf(dn, a0, b0), 0.0f);
        float t1 = fmaxf(fmaf(dn, a1, b1), 0.0f);
        if (half == 0) h2u[(size_t)n * 32 + fb] = packbf(t0, t1);
        n = n2; rs = rs2; re = re2; cnt0 = cnt2; s = s2;
    }
}

// Dense hw2 = dinv * (h2 @ W2) via MFMA. Wave tile = 16 nodes x 64 cols.
// Layouts (gfx950 16x16x32 bf16): A lane: row=lane&15, k=(lane>>4)*8+j;
// B lane: col=lane&15, same k; C/D: col=lane&15, row=(lane>>4)*4+reg (m89).
__global__ __launch_bounds__(256) void k_gemm64_mfma(
    const unsigned* __restrict__ h2u, const float* __restrict__ dinv,
    const unsigned* __restrict__ wp, unsigned* __restrict__ hw2, int N) {
    int lane = threadIdx.x & 63, wave = threadIdx.x >> 6;
    int r16 = lane & 15, kg = lane >> 4;
    bf16x8 bfrag[2][4];                          // [kstep][col-tile], 32 VGPR
    #pragma unroll
    for (int ks = 0; ks < 2; ++ks)
        #pragma unroll
        for (int ct = 0; ct < 4; ++ct) {
            int d = ct * 16 + r16;
            uint4 u = *(const uint4*)&wp[d * 32 + ks * 16 + kg * 4];
            bfrag[ks][ct] = *(bf16x8*)&u;
        }
    int tiles = (N + 15) >> 4;
    int stride = gridDim.x * 4;
    for (int t = blockIdx.x * 4 + wave; t < tiles; t += stride) {
        int nbase = t * 16;
        f32x4 acc[4];
        #pragma unroll
        for (int ct = 0; ct < 4; ++ct) acc[ct] = (f32x4)0.f;
        #pragma unroll
        for (int ks = 0; ks < 2; ++ks) {
            int arow = min(nbase + r16, N - 1);
            uint4 ua = *(const uint4*)&h2u[(size_t)arow * 32 + ks * 16 + kg * 4];
            bf16x8 afrag = *(bf16x8*)&ua;
            #pragma unroll
            for (int ct = 0; ct < 4; ++ct)
                acc[ct] = __builtin_amdgcn_mfma_f32_16x16x32_bf16(
                    afrag, bfrag[ks][ct], acc[ct], 0, 0, 0);
        }
        #pragma unroll
        for (int r = 0; r < 4; ++r) {
            int node = nbase + kg * 4 + r;       // C/D row for this lane/reg
            float dn = dinv[min(node, N - 1)];
            #pragma unroll
            for (int ct = 0; ct < 4; ++ct) {
                float v = dn * acc[ct][r];
                float v2 = __shfl_down(v, 1);    // col+1 lives in lane+1
                if (!(lane & 1) && node < N)
                    hw2[(size_t)node * 32 + ct * 8 + (r16 >> 1)] = packbf(v, v2);
            }
        }
    }
}

// Gather hw2 + relu + W3 (64x3) reduce -> hw3 float4.
__global__ __launch_bounds__(256, 4) void k_agg2(
    const unsigned* __restrict__ hw_in, const int* __restrict__ rowptr,
    const int* __restrict__ col, const float* __restrict__ dinv,
    const float* __restrict__ bias, const float* __restrict__ W3,
    float4* __restrict__ hw3, int N) {
    int lane = threadIdx.x & 63, wave = threadIdx.x >> 6;
    int fb = lane & 31, half = lane >> 5;
    int d0 = 2 * fb, d1 = 2 * fb + 1;
    float wa0 = W3[d0 * 3 + 0], wa1 = W3[d0 * 3 + 1], wa2 = W3[d0 * 3 + 2];
    float wb0 = W3[d1 * 3 + 0], wb1 = W3[d1 * 3 + 1], wb2 = W3[d1 * 3 + 2];
    float b0 = bias[d0], b1 = bias[d1];
    int stride = gridDim.x * 4;
    int n = blockIdx.x * 4 + wave;
    int rs = 0, re = 0;
    if (n < N) { rs = rowptr[n]; re = rowptr[n + 1]; }
    int cnt0 = min(64, re - rs);
    int s = (cnt0 > 0) ? col[rs + min(lane, cnt0 - 1)] : 0;
    while (n < N) {
        int n2 = n + stride;
        int rs2 = 0, re2 = 0;
        if (n2 < N) { rs2 = rowptr[n2]; re2 = rowptr[n2 + 1]; }
        int cnt2 = min(64, re2 - rs2);
        int s2 = (cnt2 > 0) ? col[rs2 + min(lane, cnt2 - 1)] : 0;
        unsigned sw = hw_in[(size_t)n * 32 + fb];
        float a0 = 0.f, a1 = 0.f;
        gather16(hw_in, s, cnt0, fb, half, a0, a1);
        for (int base = rs + 64; base < re; base += 64) {
            int cc = min(64, re - base);
            int sx = col[base + min(lane, cc - 1)];
            gather16(hw_in, sx, cc, fb, half, a0, a1);
        }
        a0 += __shfl_xor(a0, 32);
        a1 += __shfl_xor(a1, 32);
        a0 += blo(sw); a1 += bhi(sw);
        float dn = dinv[n];
        float t0 = fmaxf(fmaf(dn, a0, b0), 0.0f);
        float t1 = fmaxf(fmaf(dn, a1, b1), 0.0f);
        float p0 = fmaf(t0, wa0, t1 * wb0);
        float p1 = fmaf(t0, wa1, t1 * wb1);
        float p2 = fmaf(t0, wa2, t1 * wb2);
        #pragma unroll
        for (int off = 16; off; off >>= 1) {     // halves identical: reduce 32
            p0 += __shfl_xor(p0, off);
            p1 += __shfl_xor(p1, off);
            p2 += __shfl_xor(p2, off);
        }
        if (lane == 0) hw3[n] = make_float4(dn * p0, dn * p1, dn * p2, 0.f);
        n = n2; rs = rs2; re = re2; cnt0 = cnt2; s = s2;
    }
}

__global__ __launch_bounds__(256) void k_final(
    const float4* __restrict__ hw3, const int* __restrict__ rowptr,
    const int* __restrict__ col, const float* __restrict__ dinv,
    const float* __restrict__ b3, const float* __restrict__ x,
    const float* __restrict__ pos, float* __restrict__ out, int N) {
    int lane = threadIdx.x & 63, wave = threadIdx.x >> 6;
    int n = blockIdx.x * 4 + wave;
    if (n >= N) return;
    int rs = rowptr[n], re = rowptr[n + 1];
    float a0 = 0.f, a1 = 0.f, a2 = 0.f;
    for (int i = rs + lane; i < re; i += 64) {
        float4 v = hw3[col[i]];
        a0 += v.x; a1 += v.y; a2 += v.z;
    }
    #pragma unroll
    for (int off = 32; off; off >>= 1) {
        a0 += __shfl_xor(a0, off);
        a1 += __shfl_xor(a1, off);
        a2 += __shfl_xor(a2, off);
    }
    if (lane == 0) {
        float4 sv = hw3[n];
        a0 += sv.x; a1 += sv.y; a2 += sv.z;
        float dn = dinv[n];
        float o0 = fmaf(dn, a0, b3[0]);
        float o1 = fmaf(dn, a1, b3[1]);
        float o2 = fmaf(dn, a2, b3[2]);
        out[n] = x[n] + o2;
        out[N + 2 * n]     = pos[2 * n]     + o0;
        out[N + 2 * n + 1] = pos[2 * n + 1] + o1;
    }
}

extern "C" void kernel_launch(void* const* d_in, const int* in_sizes, int n_in,
                              void* d_out, int out_size, void* d_ws, size_t ws_size,
                              hipStream_t stream) {
    const float* x     = (const float*)d_in[0];
    const float* pos   = (const float*)d_in[1];
    const float* delta = (const float*)d_in[2];
    const int*   ei    = (const int*)  d_in[3];
    const float* W1    = (const float*)d_in[4];
    const float* b1    = (const float*)d_in[5];
    const float* W2    = (const float*)d_in[6];
    const float* b2    = (const float*)d_in[7];
    const float* W3    = (const float*)d_in[8];
    const float* b3    = (const float*)d_in[9];
    int N = in_sizes[0];
    int E = in_sizes[3] / 2;
    const int* src = ei;
    const int* dst = ei + E;

    char* p = (char*)d_ws;
    auto alloc = [&](size_t bytes) {
        char* r = p; p += (bytes + 255) & ~(size_t)255; return r;
    };
    int*   deg    = (int*)  alloc((size_t)N * 4);
    int*   bcur   = (int*)  alloc(256 * 4);
    int*   rowptr = (int*)  alloc((size_t)(N + 1) * 4);
    int nb1 = (N + 255) / 256;
    int*   bsum   = (int*)  alloc((size_t)nb1 * 4);
    int*   boff   = (int*)  alloc((size_t)(nb1 + 1) * 4);
    float* dinv   = (float*)alloc((size_t)N * 4);
    int*   col    = (int*)  alloc((size_t)E * 4);
    unsigned* wp  = (unsigned*)alloc(64 * 32 * 4);         // bf16-packed W2
    unsigned* hw1 = (unsigned*)alloc((size_t)N * 32 * 4);  // bf16x2 packed
    unsigned* hw2 = (unsigned*)alloc((size_t)N * 32 * 4);

    int B   = (N + BW_ - 1) >> SHIFT;   // 196 buckets for N=100K
    int cap = 2 * (E / B) + 1024;
    size_t wbytes = (size_t)B * cap * 4;                   // ~13.6MB
    size_t h2bytes = (size_t)N * 32 * 4;                   // 12.8MB
    unsigned* words = (unsigned*)alloc(wbytes > h2bytes ? wbytes : h2bytes);
    unsigned* h2u   = words;            // words dead after k_place
    float4*   hw3   = (float4*)hw1;     // hw1 dead after k_agg1

    int npb = (E + (256 * ITEMS) - 1) / (256 * ITEMS);

    hipMemsetAsync(bcur, 0, 256 * 4, stream);
    k_partition<<<npb, 256, 0, stream>>>(src, dst, E, bcur, words, cap);
    k_hist<<<B, 512, 0, stream>>>(words, bcur, cap, deg, N);
    k_scan1<<<nb1, 256, 0, stream>>>(deg, N, rowptr, bsum);
    k_scan2<<<1, 1024, 0, stream>>>(bsum, nb1, boff);
    k_scan3<<<(N + 256) / 256, 256, 0, stream>>>(boff, N, nb1, rowptr, deg, dinv);
    k_place<<<B, 512, 0, stream>>>(words, bcur, cap, rowptr, col, N);
    k_layer1<<<(N * 32 + 255) / 256, 256, 0, stream>>>(x, delta, W1, dinv, hw1, N);
    k_packw<<<8, 256, 0, stream>>>(W2, wp);
    k_agg1<<<2048, 256, 0, stream>>>(hw1, rowptr, col, dinv, b1, h2u, N);
    k_gemm64_mfma<<<1024, 256, 0, stream>>>(h2u, dinv, wp, hw2, N);
    k_agg2<<<2048, 256, 0, stream>>>(hw2, rowptr, col, dinv, b2, W3, hw3, N);
    k_final<<<(N + 3) / 4, 256, 0, stream>>>(hw3, rowptr, col, dinv, b3, x, pos,
                                             (float*)d_out, N);
}

// Round 13
// 254.651 us; speedup vs baseline: 1.2070x; 1.0290x over previous
//
#include <hip/hip_runtime.h>

// GCN 3-layer (PyG GCNConv: self-loops + D^-1/2 A D^-1/2).
// R13: (1) 4-edge-per-load gather (dwordx2; lane = quarter*16 + feat-octet;
// one load fetches 4 rows x 128B) -> load insts /2, shfl/min/addr VALU -40%;
// quarter-combine via shfl_xor(16,32). (2) Launch consolidation 13->10:
// hist+scan1 -> k_histscan; scan3+place -> k_place2; packw folded into
// k_layer1p. rowptrP aliases hw2 (dead until gemm). MFMA GEMM kept (R12 win).

#define SHIFT 9
#define BW_ (1 << SHIFT)      // 512 nodes per bucket
#define ITEMS 16              // edges per thread in k_partition

typedef __attribute__((ext_vector_type(8))) short bf16x8;
typedef __attribute__((ext_vector_type(4))) float f32x4;

__device__ __forceinline__ float blo(unsigned w) { return __uint_as_float(w << 16); }
__device__ __forceinline__ float bhi(unsigned w) { return __uint_as_float(w & 0xffff0000u); }
__device__ __forceinline__ unsigned packbf(float a, float b) {
    unsigned ua = __float_as_uint(a), ub = __float_as_uint(b);
    ua = (ua + 0x7fffu + ((ua >> 16) & 1u)) >> 16;         // RN-even
    ub = (ub + 0x7fffu + ((ub >> 16) & 1u)) & 0xffff0000u;
    return ua | ub;
}

__global__ __launch_bounds__(256) void k_partition(
    const int* __restrict__ src, const int* __restrict__ dst, int E,
    int* __restrict__ bcur, unsigned* __restrict__ words, int cap) {
    __shared__ int cnt[256];
    __shared__ int gbase[256];
    int t = threadIdx.x;
    int base = blockIdx.x * (256 * ITEMS);
    cnt[t] = 0;
    __syncthreads();
    unsigned w[ITEMS]; int b[ITEMS], r[ITEMS];
    #pragma unroll
    for (int j = 0; j < ITEMS; ++j) {
        int e = base + j * 256 + t;
        if (e < E) {
            int d = dst[e], s = src[e];
            b[j] = d >> SHIFT;
            w[j] = ((unsigned)s << SHIFT) | (unsigned)(d & (BW_ - 1));
            r[j] = atomicAdd(&cnt[b[j]], 1);     // LDS atomic
        } else b[j] = -1;
    }
    __syncthreads();
    int c = cnt[t];
    gbase[t] = c ? atomicAdd(&bcur[t], c) : 0;
    __syncthreads();
    #pragma unroll
    for (int j = 0; j < ITEMS; ++j) {
        if (b[j] >= 0) {
            int idx = gbase[b[j]] + r[j];
            if (idx < cap)
                words[(size_t)b[j] * cap + idx] = w[j];
        }
    }
}

// Fused: per-bucket LDS histogram + 512-wide exclusive scan.
// Writes deg[node], rowptrP[node] (excl-within-bucket), bsum[bucket].
__global__ __launch_bounds__(512) void k_histscan(
    const unsigned* __restrict__ words, const int* __restrict__ bcnt, int cap,
    int* __restrict__ deg, int* __restrict__ rowptrP, int* __restrict__ bsum,
    int N) {
    __shared__ int h[BW_];
    int b = blockIdx.x, t = threadIdx.x;
    h[t] = 0;
    __syncthreads();
    int n = min(bcnt[b], cap);
    const unsigned* wb = words + (size_t)b * cap;
    for (int i = t; i < n; i += 512)
        atomicAdd(&h[wb[i] & (BW_ - 1)], 1);
    __syncthreads();
    int v = h[t];
    #pragma unroll
    for (int off = 1; off < 512; off <<= 1) {
        int tmp = (t >= off) ? h[t - off] : 0; __syncthreads();
        h[t] += tmp; __syncthreads();
    }
    int node = b * BW_ + t;
    if (node < N) { deg[node] = v; rowptrP[node] = h[t] - v; }
    if (t == 511) bsum[b] = h[511];
}

// Single-block exclusive scan of bucket sums (B <= 256)
__global__ void k_scan2(const int* __restrict__ bsum, int nb, int* __restrict__ boff) {
    __shared__ int lds[256];
    int t = threadIdx.x;
    int v = (t < nb) ? bsum[t] : 0;
    lds[t] = v; __syncthreads();
    #pragma unroll
    for (int off = 1; off < 256; off <<= 1) {
        int tmp = (t >= off) ? lds[t - off] : 0; __syncthreads();
        lds[t] += tmp; __syncthreads();
    }
    if (t < nb) boff[t] = lds[t] - v;
    if (t == 0) boff[nb] = lds[255];
}

// Fused: finalize rowptr (+boff), dinv; then bucket-local CSR place.
__global__ __launch_bounds__(512) void k_place2(
    const unsigned* __restrict__ words, const int* __restrict__ bcnt, int cap,
    const int* __restrict__ rowptrP, const int* __restrict__ deg,
    const int* __restrict__ boff, int* __restrict__ rowptr,
    float* __restrict__ dinv, int* __restrict__ col, int N, int B) {
    __shared__ int cur[BW_];
    int b = blockIdx.x, t = threadIdx.x;
    int node = b * BW_ + t;
    int rp = 0;
    if (node < N) {
        rp = rowptrP[node] + boff[b];
        rowptr[node] = rp;
        dinv[node] = rsqrtf((float)deg[node] + 1.0f);
    }
    cur[t] = rp;
    if (b == 0 && t == 0) rowptr[N] = boff[B];
    __syncthreads();
    int n = min(bcnt[b], cap);
    const unsigned* wb = words + (size_t)b * cap;
    for (int i = t; i < n; i += 512) {
        unsigned w = wb[i];
        int p = atomicAdd(&cur[w & (BW_ - 1)], 1);
        col[p] = (int)(w >> SHIFT);
    }
}

// layer1 (hw1 packed bf16x2, dinv-scaled) + W2 bf16 pack fused.
__global__ void k_layer1p(const float* __restrict__ x, const float* __restrict__ delta,
                          const float* __restrict__ W1, const float* __restrict__ dinv,
                          unsigned* __restrict__ hw, const float* __restrict__ W2,
                          unsigned* __restrict__ wp, int N) {
    int idx = blockIdx.x * blockDim.x + threadIdx.x;
    int nw = N * 32;
    if (idx < nw) {
        int n = idx >> 5, f = idx & 31;
        int d0 = 2 * f, d1 = 2 * f + 1;
        float c0 = delta[0] * W1[64 + d0] + delta[1] * W1[128 + d0] +
                   delta[2] * W1[192 + d0] + delta[3] * W1[256 + d0];
        float c1 = delta[0] * W1[64 + d1] + delta[1] * W1[128 + d1] +
                   delta[2] * W1[192 + d1] + delta[3] * W1[256 + d1];
        float dn = dinv[n], xv = x[n];
        hw[idx] = packbf(dn * fmaf(xv, W1[d0], c0), dn * fmaf(xv, W1[d1], c1));
    } else if (idx < nw + 64 * 32) {
        int i = idx - nw;
        int d = i >> 5, kk = i & 31;
        wp[i] = packbf(W2[(2 * kk) * 64 + d], W2[(2 * kk + 1) * 64 + d]);
    }
}

// 4-edge-per-load gather. lane = q*16 + f: q=edge-in-group, f=feat octet
// (feats 4f..4f+3, 8B). One dwordx2 load = 4 rows x 128B across the wave.
__device__ __forceinline__ void gather4x(const unsigned* __restrict__ hw,
                                         int s, int cnt, int f, int q,
                                         float& a0, float& a1, float& a2, float& a3) {
    for (int j = 0; j < cnt; j += 16) {
        int e0 = j + q, e1 = j + 4 + q, e2 = j + 8 + q, e3 = j + 12 + q;
        int i0 = __shfl(s, min(e0, cnt - 1));
        int i1 = __shfl(s, min(e1, cnt - 1));
        int i2 = __shfl(s, min(e2, cnt - 1));
        int i3 = __shfl(s, min(e3, cnt - 1));
        uint2 u0 = *(const uint2*)&hw[(size_t)i0 * 32 + f * 2];
        uint2 u1 = *(const uint2*)&hw[(size_t)i1 * 32 + f * 2];
        uint2 u2 = *(const uint2*)&hw[(size_t)i2 * 32 + f * 2];
        uint2 u3 = *(const uint2*)&hw[(size_t)i3 * 32 + f * 2];
        if (e0 >= cnt) { u0.x = 0u; u0.y = 0u; }
        if (e1 >= cnt) { u1.x = 0u; u1.y = 0u; }
        if (e2 >= cnt) { u2.x = 0u; u2.y = 0u; }
        if (e3 >= cnt) { u3.x = 0u; u3.y = 0u; }
        a0 += (blo(u0.x) + blo(u1.x)) + (blo(u2.x) + blo(u3.x));
        a1 += (bhi(u0.x) + bhi(u1.x)) + (bhi(u2.x) + bhi(u3.x));
        a2 += (blo(u0.y) + blo(u1.y)) + (blo(u2.y) + blo(u3.y));
        a3 += (bhi(u0.y) + bhi(u1.y)) + (bhi(u2.y) + bhi(u3.y));
    }
}

// Gather + relu + pack: h2 = relu(dinv*agg + b).
__global__ __launch_bounds__(256) void k_agg1(
    const unsigned* __restrict__ hw_in, const int* __restrict__ rowptr,
    const int* __restrict__ col, const float* __restrict__ dinv,
    const float* __restrict__ bias, unsigned* __restrict__ h2u, int N) {
    int lane = threadIdx.x & 63;
    int f = lane & 15, q = lane >> 4;
    float4 bq = *(const float4*)&bias[4 * f];
    int stride = gridDim.x * 4;
    int n = blockIdx.x * 4 + (threadIdx.x >> 6);
    int rs = 0, re = 0;
    if (n < N) { rs = rowptr[n]; re = rowptr[n + 1]; }
    int cnt0 = min(64, re - rs);
    int s = (cnt0 > 0) ? col[rs + min(lane, cnt0 - 1)] : 0;
    while (n < N) {
        int n2 = n + stride;
        int rs2 = 0, re2 = 0;
        if (n2 < N) { rs2 = rowptr[n2]; re2 = rowptr[n2 + 1]; }
        int cnt2 = min(64, re2 - rs2);
        int s2 = (cnt2 > 0) ? col[rs2 + min(lane, cnt2 - 1)] : 0;  // prefetch next
        uint2 sw = *(const uint2*)&hw_in[(size_t)n * 32 + f * 2];  // self-loop
        float a0 = 0.f, a1 = 0.f, a2 = 0.f, a3 = 0.f;
        gather4x(hw_in, s, cnt0, f, q, a0, a1, a2, a3);
        for (int base = rs + 64; base < re; base += 64) {          // rare: deg>64
            int cc = min(64, re - base);
            int sx = col[base + min(lane, cc - 1)];
            gather4x(hw_in, sx, cc, f, q, a0, a1, a2, a3);
        }
        a0 += __shfl_xor(a0, 16); a0 += __shfl_xor(a0, 32);        // combine quarters
        a1 += __shfl_xor(a1, 16); a1 += __shfl_xor(a1, 32);
        a2 += __shfl_xor(a2, 16); a2 += __shfl_xor(a2, 32);
        a3 += __shfl_xor(a3, 16); a3 += __shfl_xor(a3, 32);
        a0 += blo(sw.x); a1 += bhi(sw.x); a2 += blo(sw.y); a3 += bhi(sw.y);
        float dn = dinv[n];
        float t0 = fmaxf(fmaf(dn, a0, bq.x), 0.0f);
        float t1 = fmaxf(fmaf(dn, a1, bq.y), 0.0f);
        float t2 = fmaxf(fmaf(dn, a2, bq.z), 0.0f);
        float t3 = fmaxf(fmaf(dn, a3, bq.w), 0.0f);
        if (q == 0) {
            uint2 o; o.x = packbf(t0, t1); o.y = packbf(t2, t3);
            *(uint2*)&h2u[(size_t)n * 32 + f * 2] = o;
        }
        n = n2; rs = rs2; re = re2; cnt0 = cnt2; s = s2;
    }
}

// Dense hw2 = dinv * (h2 @ W2) via MFMA (R12, unchanged).
__global__ __launch_bounds__(256) void k_gemm64_mfma(
    const unsigned* __restrict__ h2u, const float* __restrict__ dinv,
    const unsigned* __restrict__ wp, unsigned* __restrict__ hw2, int N) {
    int lane = threadIdx.x & 63, wave = threadIdx.x >> 6;
    int r16 = lane & 15, kg = lane >> 4;
    bf16x8 bfrag[2][4];
    #pragma unroll
    for (int ks = 0; ks < 2; ++ks)
        #pragma unroll
        for (int ct = 0; ct < 4; ++ct) {
            int d = ct * 16 + r16;
            uint4 u = *(const uint4*)&wp[d * 32 + ks * 16 + kg * 4];
            bfrag[ks][ct] = *(bf16x8*)&u;
        }
    int tiles = (N + 15) >> 4;
    int stride = gridDim.x * 4;
    for (int t = blockIdx.x * 4 + wave; t < tiles; t += stride) {
        int nbase = t * 16;
        f32x4 acc[4];
        #pragma unroll
        for (int ct = 0; ct < 4; ++ct) acc[ct] = (f32x4)0.f;
        #pragma unroll
        for (int ks = 0; ks < 2; ++ks) {
            int arow = min(nbase + r16, N - 1);
            uint4 ua = *(const uint4*)&h2u[(size_t)arow * 32 + ks * 16 + kg * 4];
            bf16x8 afrag = *(bf16x8*)&ua;
            #pragma unroll
            for (int ct = 0; ct < 4; ++ct)
                acc[ct] = __builtin_amdgcn_mfma_f32_16x16x32_bf16(
                    afrag, bfrag[ks][ct], acc[ct], 0, 0, 0);
        }
        #pragma unroll
        for (int r = 0; r < 4; ++r) {
            int node = nbase + kg * 4 + r;
            float dn = dinv[min(node, N - 1)];
            #pragma unroll
            for (int ct = 0; ct < 4; ++ct) {
                float v = dn * acc[ct][r];
                float v2 = __shfl_down(v, 1);
                if (!(lane & 1) && node < N)
                    hw2[(size_t)node * 32 + ct * 8 + (r16 >> 1)] = packbf(v, v2);
            }
        }
    }
}

// Gather hw2 + relu + W3 (64x3) reduce -> hw3 float4.
__global__ __launch_bounds__(256, 4) void k_agg2(
    const unsigned* __restrict__ hw_in, const int* __restrict__ rowptr,
    const int* __restrict__ col, const float* __restrict__ dinv,
    const float* __restrict__ bias, const float* __restrict__ W3,
    float4* __restrict__ hw3, int N) {
    int lane = threadIdx.x & 63;
    int f = lane & 15, q = lane >> 4;
    float4 bq = *(const float4*)&bias[4 * f];
    float w00 = W3[(4*f+0)*3+0], w01 = W3[(4*f+0)*3+1], w02 = W3[(4*f+0)*3+2];
    float w10 = W3[(4*f+1)*3+0], w11 = W3[(4*f+1)*3+1], w12 = W3[(4*f+1)*3+2];
    float w20 = W3[(4*f+2)*3+0], w21 = W3[(4*f+2)*3+1], w22 = W3[(4*f+2)*3+2];
    float w30 = W3[(4*f+3)*3+0], w31 = W3[(4*f+3)*3+1], w32 = W3[(4*f+3)*3+2];
    int stride = gridDim.x * 4;
    int n = blockIdx.x * 4 + (threadIdx.x >> 6);
    int rs = 0, re = 0;
    if (n < N) { rs = rowptr[n]; re = rowptr[n + 1]; }
    int cnt0 = min(64, re - rs);
    int s = (cnt0 > 0) ? col[rs + min(lane, cnt0 - 1)] : 0;
    while (n < N) {
        int n2 = n + stride;
        int rs2 = 0, re2 = 0;
        if (n2 < N) { rs2 = rowptr[n2]; re2 = rowptr[n2 + 1]; }
        int cnt2 = min(64, re2 - rs2);
        int s2 = (cnt2 > 0) ? col[rs2 + min(lane, cnt2 - 1)] : 0;
        uint2 sw = *(const uint2*)&hw_in[(size_t)n * 32 + f * 2];
        float a0 = 0.f, a1 = 0.f, a2 = 0.f, a3 = 0.f;
        gather4x(hw_in, s, cnt0, f, q, a0, a1, a2, a3);
        for (int base = rs + 64; base < re; base += 64) {
            int cc = min(64, re - base);
            int sx = col[base + min(lane, cc - 1)];
            gather4x(hw_in, sx, cc, f, q, a0, a1, a2, a3);
        }
        a0 += __shfl_xor(a0, 16); a0 += __shfl_xor(a0, 32);
        a1 += __shfl_xor(a1, 16); a1 += __shfl_xor(a1, 32);
        a2 += __shfl_xor(a2, 16); a2 += __shfl_xor(a2, 32);
        a3 += __shfl_xor(a3, 16); a3 += __shfl_xor(a3, 32);
        a0 += blo(sw.x); a1 += bhi(sw.x); a2 += blo(sw.y); a3 += bhi(sw.y);
        float dn = dinv[n];
        float t0 = fmaxf(fmaf(dn, a0, bq.x), 0.0f);
        float t1 = fmaxf(fmaf(dn, a1, bq.y), 0.0f);
        float t2 = fmaxf(fmaf(dn, a2, bq.z), 0.0f);
        float t3 = fmaxf(fmaf(dn, a3, bq.w), 0.0f);
        float p0 = fmaf(t0, w00, fmaf(t1, w10, fmaf(t2, w20, t3 * w30)));
        float p1 = fmaf(t0, w01, fmaf(t1, w11, fmaf(t2, w21, t3 * w31)));
        float p2 = fmaf(t0, w02, fmaf(t1, w12, fmaf(t2, w22, t3 * w32)));
        #pragma unroll
        for (int off = 8; off; off >>= 1) {      // reduce over f (quarters identical)
            p0 += __shfl_xor(p0, off);
            p1 += __shfl_xor(p1, off);
            p2 += __shfl_xor(p2, off);
        }
        if (lane == 0) hw3[n] = make_float4(dn * p0, dn * p1, dn * p2, 0.f);
        n = n2; rs = rs2; re = re2; cnt0 = cnt2; s = s2;
    }
}

__global__ __launch_bounds__(256) void k_final(
    const float4* __restrict__ hw3, const int* __restrict__ rowptr,
    const int* __restrict__ col, const float* __restrict__ dinv,
    const float* __restrict__ b3, const float* __restrict__ x,
    const float* __restrict__ pos, float* __restrict__ out, int N) {
    int lane = threadIdx.x & 63, wave = threadIdx.x >> 6;
    int n = blockIdx.x * 4 + wave;
    if (n >= N) return;
    int rs = rowptr[n], re = rowptr[n + 1];
    float a0 = 0.f, a1 = 0.f, a2 = 0.f;
    for (int i = rs + lane; i < re; i += 64) {
        float4 v = hw3[col[i]];
        a0 += v.x; a1 += v.y; a2 += v.z;
    }
    #pragma unroll
    for (int off = 32; off; off >>= 1) {
        a0 += __shfl_xor(a0, off);
        a1 += __shfl_xor(a1, off);
        a2 += __shfl_xor(a2, off);
    }
    if (lane == 0) {
        float4 sv = hw3[n];
        a0 += sv.x; a1 += sv.y; a2 += sv.z;
        float dn = dinv[n];
        float o0 = fmaf(dn, a0, b3[0]);
        float o1 = fmaf(dn, a1, b3[1]);
        float o2 = fmaf(dn, a2, b3[2]);
        out[n] = x[n] + o2;
        out[N + 2 * n]     = pos[2 * n]     + o0;
        out[N + 2 * n + 1] = pos[2 * n + 1] + o1;
    }
}

extern "C" void kernel_launch(void* const* d_in, const int* in_sizes, int n_in,
                              void* d_out, int out_size, void* d_ws, size_t ws_size,
                              hipStream_t stream) {
    const float* x     = (const float*)d_in[0];
    const float* pos   = (const float*)d_in[1];
    const float* delta = (const float*)d_in[2];
    const int*   ei    = (const int*)  d_in[3];
    const float* W1    = (const float*)d_in[4];
    const float* b1    = (const float*)d_in[5];
    const float* W2    = (const float*)d_in[6];
    const float* b2    = (const float*)d_in[7];
    const float* W3    = (const float*)d_in[8];
    const float* b3    = (const float*)d_in[9];
    int N = in_sizes[0];
    int E = in_sizes[3] / 2;
    const int* src = ei;
    const int* dst = ei + E;

    char* p = (char*)d_ws;
    auto alloc = [&](size_t bytes) {
        char* r = p; p += (bytes + 255) & ~(size_t)255; return r;
    };
    int*   deg    = (int*)  alloc((size_t)N * 4);
    int*   bcur   = (int*)  alloc(256 * 4);
    int*   rowptr = (int*)  alloc((size_t)(N + 1) * 4);
    int*   bsum   = (int*)  alloc(256 * 4);
    int*   boff   = (int*)  alloc(257 * 4);
    float* dinv   = (float*)alloc((size_t)N * 4);
    int*   col    = (int*)  alloc((size_t)E * 4);
    unsigned* wp  = (unsigned*)alloc(64 * 32 * 4);         // bf16-packed W2
    unsigned* hw1 = (unsigned*)alloc((size_t)N * 32 * 4);  // bf16x2 packed
    unsigned* hw2 = (unsigned*)alloc((size_t)N * 32 * 4);

    int B   = (N + BW_ - 1) >> SHIFT;   // 196 buckets for N=100K (<=256)
    int cap = 2 * (E / B) + 1024;
    size_t wbytes = (size_t)B * cap * 4;                   // ~13.6MB
    size_t h2bytes = (size_t)N * 32 * 4;                   // 12.8MB
    unsigned* words = (unsigned*)alloc(wbytes > h2bytes ? wbytes : h2bytes);
    unsigned* h2u   = words;            // words dead after k_place2
    float4*   hw3   = (float4*)hw1;     // hw1 dead after k_agg1
    int*  rowptrP   = (int*)hw2;        // hw2 dead until k_gemm64_mfma

    int npb = (E + (256 * ITEMS) - 1) / (256 * ITEMS);

    hipMemsetAsync(bcur, 0, 256 * 4, stream);
    k_partition<<<npb, 256, 0, stream>>>(src, dst, E, bcur, words, cap);
    k_histscan<<<B, 512, 0, stream>>>(words, bcur, cap, deg, rowptrP, bsum, N);
    k_scan2<<<1, 256, 0, stream>>>(bsum, B, boff);
    k_place2<<<B, 512, 0, stream>>>(words, bcur, cap, rowptrP, deg, boff,
                                    rowptr, dinv, col, N, B);
    k_layer1p<<<(N * 32 + 64 * 32 + 255) / 256, 256, 0, stream>>>(
        x, delta, W1, dinv, hw1, W2, wp, N);
    k_agg1<<<2048, 256, 0, stream>>>(hw1, rowptr, col, dinv, b1, h2u, N);
    k_gemm64_mfma<<<1024, 256, 0, stream>>>(h2u, dinv, wp, hw2, N);
    k_agg2<<<2048, 256, 0, stream>>>(hw2, rowptr, col, dinv, b2, W3, hw3, N);
    k_final<<<(N + 3) / 4, 256, 0, stream>>>(hw3, rowptr, col, dinv, b3, x, pos,
                                             (float*)d_out, N);
}